// Round 10
// baseline (334.312 us; speedup 1.0000x reference)
//
#include <hip/hip_runtime.h>

// ---------------------------------------------------------------------------
// AttentionBlock: GroupNorm(32) -> q,k,v = xn@W+b -> softmax(q k^T / sqrt(C)) v
//                 -> out@wp+bp + x.   B=2, H=W=64, C=512, S=4096 per batch.
// Round 10 (from r9's 310 us):
//   - REVERT r9's S LDS-transpose epilogue (regressed 82->91: 2 extra
//     barriers + 64 ds_writes on the critical path beat the scattered-store
//     cost it removed). Back to r8 direct stores.
//   - gemm128_k __launch_bounds__(256,2) -> (256,4): all modes use <=72
//     VGPR, LDS 32 KB; nothing should stop 4 blocks/CU residency. The
//     ~1540 cyc/block-step constant across S/PV/r7 is the vmcnt(0) barrier
//     drain at ~2 blocks/CU overlap; 4 blocks/CU halves its exposure.
//   Everything else identical to r9 (gn partial-sums, TM=64 OUT, etc).
// ---------------------------------------------------------------------------

typedef __bf16 bf16_t;
typedef __bf16 bf16x8 __attribute__((ext_vector_type(8)));
typedef __bf16 bf16x4 __attribute__((ext_vector_type(4)));
typedef float  f32x4  __attribute__((ext_vector_type(4)));

__device__ __forceinline__ bf16x8 ld8(const bf16_t* p) {
    return *reinterpret_cast<const bf16x8*>(p);
}
__device__ __forceinline__ f32x4 mfma16(bf16x8 a, bf16x8 b, f32x4 c) {
    return __builtin_amdgcn_mfma_f32_16x16x32_bf16(a, b, c, 0, 0, 0);
}
__device__ __forceinline__ void gload16(const bf16_t* gp, bf16_t* lp) {
    // HW semantics: LDS dest = wave-uniform base + laneid*16B; gp per-lane.
    __builtin_amdgcn_global_load_lds(
        (const __attribute__((address_space(1))) void*)gp,
        (__attribute__((address_space(3))) void*)lp, 16, 0, 0);
}

#define NPIX 8192      // B*H*W
#define C512 512
#define SEQ  4096      // H*W per batch
#define QSCALE 0.044194173824159216f   // 512^-0.5

// ---------------- GroupNorm partial sums: 512 blocks (8 slices x 64 bg) -----
__global__ __launch_bounds__(256) void gn_sum_k(const float* __restrict__ x,
                                                float* __restrict__ accum) {
    int bg    = blockIdx.x >> 3;        // 0..63 = b*32+g
    int slice = blockIdx.x & 7;         // 512-pixel slice
    int b = bg >> 5, g = bg & 31;
    const float* xp = x + (size_t)b * SEQ * C512 + g * 16;
    float s = 0.f, s2 = 0.f;
    #pragma unroll
    for (int pp = 0; pp < 2; pp++) {
        int p = slice * 512 + pp * 256 + threadIdx.x;
        const float4* q = reinterpret_cast<const float4*>(xp + (size_t)p * C512);
        #pragma unroll
        for (int i = 0; i < 4; i++) {
            float4 v = q[i];
            s  += v.x + v.y + v.z + v.w;
            s2 += v.x*v.x + v.y*v.y + v.z*v.z + v.w*v.w;
        }
    }
    #pragma unroll
    for (int off = 32; off >= 1; off >>= 1) {
        s  += __shfl_down(s, off);
        s2 += __shfl_down(s2, off);
    }
    __shared__ float rs[4], rs2[4];
    int wave = threadIdx.x >> 6;
    if ((threadIdx.x & 63) == 0) { rs[wave] = s; rs2[wave] = s2; }
    __syncthreads();
    if (threadIdx.x == 0) {
        float S = rs[0] + rs[1] + rs[2] + rs[3];
        float S2 = rs2[0] + rs2[1] + rs2[2] + rs2[3];
        atomicAdd(&accum[bg * 2],     S);
        atomicAdd(&accum[bg * 2 + 1], S2);
    }
}

// ---------------- weights: fp32 (k,n) -> bf16 transposed (n,k) --------------
__global__ __launch_bounds__(256) void wt_conv_k(const float* wq, const float* wk,
                                                 const float* wv, const float* wp,
                                                 bf16_t* wqkvT, bf16_t* wpT) {
    int y = blockIdx.y;
    const float* w = (y == 0) ? wq : (y == 1) ? wk : (y == 2) ? wv : wp;
    float scale = (y == 0) ? QSCALE : 1.0f;
    int tid = blockIdx.x * 256 + threadIdx.x;     // 262144 total
    int n = tid >> 9, k = tid & 511;
    bf16_t val = (bf16_t)(w[(size_t)k * C512 + n] * scale);
    if (y < 3) wqkvT[((size_t)y * C512 + n) * C512 + k] = val;
    else       wpT[(size_t)n * C512 + k] = val;
}

// ---------------- merged qkv bias (Q segment pre-scaled) --------------------
__global__ __launch_bounds__(256) void bias_merge_k(const float* bq, const float* bk,
                                                    const float* bv, float* bqkv) {
    int i = blockIdx.x * 256 + threadIdx.x;       // 1536
    float v = (i < 512) ? bq[i] * QSCALE : (i < 1024) ? bk[i - 512] : bv[i - 1024];
    bqkv[i] = v;
}

// ---------------- xn = groupnorm(x)*gamma+beta -> bf16 ----------------------
// accum holds raw (sum, sumsq) per (b,g); finalize inline.
__global__ __launch_bounds__(256) void xn_k(const float* __restrict__ x,
                                            const float* __restrict__ accum,
                                            const float* __restrict__ gamma,
                                            const float* __restrict__ beta,
                                            bf16_t* __restrict__ xn) {
    size_t idx = ((size_t)blockIdx.x * 256 + threadIdx.x) * 4;   // elem index
    int c = (int)(idx & 511);
    size_t pix = idx >> 9;
    int b = (int)(pix >> 12);
    int g = c >> 4;
    float sum = accum[(b * 32 + g) * 2];
    float ssq = accum[(b * 32 + g) * 2 + 1];
    float mean = sum * (1.f / 65536.f);
    float var  = ssq * (1.f / 65536.f) - mean * mean;
    float rstd = rsqrtf(var + 1e-5f);
    float4 v  = *reinterpret_cast<const float4*>(x + idx);
    float4 gm = *reinterpret_cast<const float4*>(gamma + c);
    float4 bt = *reinterpret_cast<const float4*>(beta + c);
    bf16x4 o;
    o[0] = (bf16_t)((v.x - mean) * rstd * gm.x + bt.x);
    o[1] = (bf16_t)((v.y - mean) * rstd * gm.y + bt.y);
    o[2] = (bf16_t)((v.z - mean) * rstd * gm.z + bt.z);
    o[3] = (bf16_t)((v.w - mean) * rstd * gm.w + bt.w);
    *reinterpret_cast<bf16x4*>(xn + idx) = o;
}

// ---------------- unified TMx128-tile GEMM (m97 structure) ------------------
// C[TM,128] per block = A[TM,K] x B^T where B is n-major [n][k].
// Block 256 thr / 4 waves (2x2 of (TM/2)x64). BK=32. global_load_lds staging
// into fragment-major LDS (layout proven r2-r8; conflict-free).
// __launch_bounds__(256,4): VGPR cap 128 under both interpretations (all
// modes use <=72); LDS 32 KB -> 4 blocks/CU residency possible.
// MODE 0: QKV (TM=128) — A=xn, B=wqkvT(1536x512). Epilogue: +bqkv; cols
//                0-511 -> Q, 512-1023 -> K (row-major), 1024-1535 -> VT.
// MODE 1: S   (TM=128) — per batch z: A=Q, B=K. Epilogue: P=exp(min(s,20))
//                direct bf16 stores (r8 style); fp32 row-sums shfl-reduced,
//                atomicAdd into lsum.
// MODE 2: PV  (TM=128) — split-K x4: z=b*4+sp. A=P(lda=SEQ), B=VT(ldb=SEQ).
//                Unnormalized bf16 partial into Op[sp].
// MODE 3: OUT (TM=64)  — A=O, B=wpT. Epilogue: +bp +resid, fp32 out.
template <int MODE>
__global__ __launch_bounds__(256, 4) void gemm128_k(
        const bf16_t* __restrict__ Aall, const bf16_t* __restrict__ Ball,
        const float* __restrict__ bias, const float* __restrict__ resid,
        void* __restrict__ out0, void* __restrict__ out1,
        void* __restrict__ out2, void* __restrict__ out3,
        float* __restrict__ lsum) {
    constexpr int TM  = (MODE == 3) ? 64 : 128;
    constexpr int ASZ = TM * 32;          // A elems per buffer
    constexpr int ACH = TM / 16;          // A chunks per step
    constexpr int CPW = (ACH + 8) / 4;    // staging chunks per wave
    constexpr int MI  = TM / 32;          // m-tiles per wave
    __shared__ bf16_t smem[2 * ASZ + 8192];   // A dbuf + B dbuf

    int lane = threadIdx.x & 63;
    int w    = threadIdx.x >> 6;          // 4 waves, 2x2
    int wr   = w >> 1, wc = w & 1;
    int lrow = lane & 15, quad = lane >> 4;
    int bz   = blockIdx.z;

    const bf16_t* A;
    const bf16_t* B;
    size_t lda, ldb;
    int ksteps, kofs = 0, zb = bz, sp = 0;
    if (MODE == 0)      { A = Aall;                         B = Ball;                        lda = 512;  ldb = 512;  ksteps = 16; }
    else if (MODE == 1) { A = Aall + (size_t)bz*SEQ*C512;   B = Ball + (size_t)bz*SEQ*C512;  lda = 512;  ldb = 512;  ksteps = 16; }
    else if (MODE == 2) { zb = bz >> 2; sp = bz & 3;
                          A = Aall + (size_t)zb*SEQ*SEQ;    B = Ball + (size_t)zb*C512*SEQ;  lda = SEQ;  ldb = SEQ;  ksteps = 32; kofs = sp * 1024; }
    else                { A = Aall;                         B = Ball;                        lda = 512;  ldb = 512;  ksteps = 16; }

    int bm = blockIdx.x * TM, bn = blockIdx.y * 128;

    // stage K-step ks into buffer buf: ACH A-chunks + 8 B-chunks
    auto stage = [&](int buf, int ks) {
        size_t k0 = (size_t)kofs + (size_t)ks * 32;
        #pragma unroll
        for (int ii = 0; ii < CPW; ii++) {
            int c = w * CPW + ii;
            if (c < ACH) {
                const bf16_t* gpA = A + (size_t)(bm + c * 16 + lrow) * lda + k0 + quad * 8;
                gload16(gpA, &smem[buf * ASZ + c * 512]);
            } else {
                int cb = c - ACH;
                const bf16_t* gpB = B + (size_t)(bn + cb * 16 + lrow) * ldb + k0 + quad * 8;
                gload16(gpB, &smem[2 * ASZ + buf * 4096 + cb * 512]);
            }
        }
    };

    f32x4 acc[MI][4] = {};

    stage(0, 0);

    for (int ks = 0; ks < ksteps; ks++) {
        int cur = ks & 1;
        __syncthreads();                 // drains stage(ks); WAR for dbuf
        if (ks + 1 < ksteps) stage(1 - cur, ks + 1);

        const bf16_t* al = &smem[cur * ASZ + (wr * MI) * 512];
        const bf16_t* bl = &smem[2 * ASZ + cur * 4096 + (wc * 4) * 512];
        bf16x8 af[MI], bf[4];
        #pragma unroll
        for (int m = 0; m < MI; m++) af[m] = ld8(al + m * 512 + lane * 8);
        #pragma unroll
        for (int n = 0; n < 4; n++) bf[n] = ld8(bl + n * 512 + lane * 8);
        #pragma unroll
        for (int m = 0; m < MI; m++)
            #pragma unroll
            for (int n = 0; n < 4; n++)
                acc[m][n] = mfma16(af[m], bf[n], acc[m][n]);
    }

    // ---- epilogue; C/D layout: col=lane&15, row=quad*4+reg ----
    float rs[MI][4];                     // MODE 1 per-row partial sums
    if (MODE == 1) {
        #pragma unroll
        for (int m = 0; m < MI; m++)
            #pragma unroll
            for (int i = 0; i < 4; i++) rs[m][i] = 0.f;
    }

    #pragma unroll
    for (int m = 0; m < MI; m++) {
        int rowb = bm + wr * (TM / 2) + m * 16 + quad * 4;
        #pragma unroll
        for (int n = 0; n < 4; n++) {
            int col = bn + wc * 64 + n * 16 + lrow;
            #pragma unroll
            for (int i = 0; i < 4; i++) {
                int row = rowb + i;
                float v = acc[m][n][i];
                if (MODE == 0) {
                    int seg = col >> 9, c = col & 511;
                    bf16_t val = (bf16_t)(v + bias[col]);
                    if (seg == 0) {
                        ((bf16_t*)out0)[(size_t)row * C512 + c] = val;
                    } else if (seg == 1) {
                        ((bf16_t*)out1)[(size_t)row * C512 + c] = val;
                    } else {
                        int b = row >> 12, s = row & 4095;
                        ((bf16_t*)out2)[((size_t)(b * C512 + c)) * SEQ + s] = val;
                    }
                } else if (MODE == 1) {
                    float p = __expf(fminf(v, 20.0f));
                    bf16_t* P = (bf16_t*)out0 + (size_t)bz * SEQ * SEQ;
                    P[(size_t)row * SEQ + col] = (bf16_t)p;
                    rs[m][i] += p;
                } else if (MODE == 2) {
                    bf16_t* Ops = (bf16_t*)((sp == 0) ? out0 : (sp == 1) ? out1
                                          : (sp == 2) ? out2 : out3);
                    Ops[((size_t)zb * SEQ + row) * C512 + col] = (bf16_t)v;
                } else {
                    size_t idx = (size_t)row * C512 + col;
                    ((float*)out0)[idx] = v + bias[col] + resid[idx];
                }
            }
        }
    }

    if (MODE == 1) {
        // reduce row sums over the 16 col-lanes, one atomicAdd/row/wave
        #pragma unroll
        for (int m = 0; m < MI; m++) {
            #pragma unroll
            for (int i = 0; i < 4; i++) {
                float r = rs[m][i];
                r += __shfl_xor(r, 1);
                r += __shfl_xor(r, 2);
                r += __shfl_xor(r, 4);
                r += __shfl_xor(r, 8);
                if (lrow == 0) {
                    int row = bm + wr * 64 + m * 16 + quad * 4 + i;
                    atomicAdd(&lsum[(size_t)bz * SEQ + row], r);
                }
            }
        }
    }
}

// ---------------- combine PV split-K partials: O = Sum(Op)/lsum -------------
__global__ __launch_bounds__(256) void attn_combine_k(const bf16_t* __restrict__ Op0,
                                                      const bf16_t* __restrict__ Op1,
                                                      const bf16_t* __restrict__ Op2,
                                                      const bf16_t* __restrict__ Op3,
                                                      const float* __restrict__ lsum,
                                                      bf16_t* __restrict__ O) {
    int idx = blockIdx.x * 256 + threadIdx.x;    // 524288 threads
    int row = idx >> 6;                          // global row 0..8191
    int c8  = (idx & 63) << 3;
    float inv = 1.0f / lsum[row];
    size_t base = (size_t)row * C512 + c8;
    bf16x8 o0 = ld8(Op0 + base), o1 = ld8(Op1 + base);
    bf16x8 o2 = ld8(Op2 + base), o3 = ld8(Op3 + base);
    bf16x8 o;
    #pragma unroll
    for (int j = 0; j < 8; j++)
        o[j] = (bf16_t)(((float)o0[j] + (float)o1[j] +
                         (float)o2[j] + (float)o3[j]) * inv);
    *reinterpret_cast<bf16x8*>(O + base) = o;
}

// ---------------------------------------------------------------------------
extern "C" void kernel_launch(void* const* d_in, const int* in_sizes, int n_in,
                              void* d_out, int out_size, void* d_ws, size_t ws_size,
                              hipStream_t stream) {
    const float* x     = (const float*)d_in[0];
    const float* gamma = (const float*)d_in[1];
    const float* beta  = (const float*)d_in[2];
    const float* wq = (const float*)d_in[3];  const float* bq = (const float*)d_in[4];
    const float* wk = (const float*)d_in[5];  const float* bk = (const float*)d_in[6];
    const float* wv = (const float*)d_in[7];  const float* bv = (const float*)d_in[8];
    const float* wp = (const float*)d_in[9];  const float* bp = (const float*)d_in[10];
    float* out = (float*)d_out;

    char* ws = (char*)d_ws;
    size_t off = 0;
    float*  bqkv   = (float*)(ws + off);   off += 1536 * sizeof(float);
    float*  lsum   = (float*)(ws + off);   off += (size_t)NPIX * sizeof(float);
    float*  accum  = (float*)(ws + off);   off += 128 * sizeof(float);
    bf16_t* xn     = (bf16_t*)(ws + off);  off += (size_t)NPIX * C512 * 2;  // later Ob
    bf16_t* wqkvT  = (bf16_t*)(ws + off);  off += (size_t)3 * C512 * C512 * 2;
    bf16_t* wpT    = (bf16_t*)(ws + off);  off += (size_t)C512 * C512 * 2;
    bf16_t* Qb     = (bf16_t*)(ws + off);  off += (size_t)NPIX * C512 * 2;  // later Op0
    bf16_t* Kb     = (bf16_t*)(ws + off);  off += (size_t)NPIX * C512 * 2;  // later Op1
    bf16_t* VTb    = (bf16_t*)(ws + off);  off += (size_t)NPIX * C512 * 2;
    bf16_t* Op2    = (bf16_t*)(ws + off);  off += (size_t)NPIX * C512 * 2;
    bf16_t* Op3    = (bf16_t*)(ws + off);  off += (size_t)NPIX * C512 * 2;
    bf16_t* P      = (bf16_t*)(ws + off);  off += (size_t)2 * SEQ * SEQ * 2;  // 64 MB
    bf16_t* Ob  = xn;    // xn dead after QKV GEMM
    bf16_t* Op0 = Qb;    // Q dead after S GEMM
    bf16_t* Op1 = Kb;    // K dead after S GEMM

    // zero lsum + accum (contiguous)
    hipMemsetAsync(lsum, 0, (size_t)(NPIX + 128) * sizeof(float), stream);

    gn_sum_k<<<512, 256, 0, stream>>>(x, accum);
    wt_conv_k<<<dim3(1024, 4), 256, 0, stream>>>(wq, wk, wv, wp, wqkvT, wpT);
    bias_merge_k<<<6, 256, 0, stream>>>(bq, bk, bv, bqkv);
    xn_k<<<4096, 256, 0, stream>>>(x, accum, gamma, beta, xn);

    // QKV: (8192 x 1536) = xn @ wqkvT^T
    gemm128_k<0><<<dim3(64, 12, 1), 256, 0, stream>>>(
        xn, wqkvT, bqkv, nullptr, Qb, Kb, VTb, nullptr, nullptr);

    // S/P: per batch (4096 x 4096) = Q @ K^T, epilogue exp -> P, rowsums->lsum
    gemm128_k<1><<<dim3(32, 32, 2), 256, 0, stream>>>(
        Qb, Kb, nullptr, nullptr, P, nullptr, nullptr, nullptr, lsum);

    // PV: split-K x4 per batch (4096 x 512) = P @ VT^T -> 4 bf16 partials
    gemm128_k<2><<<dim3(32, 4, 8), 256, 0, stream>>>(
        P, VTb, nullptr, nullptr, Op0, Op1, Op2, Op3, nullptr);

    // combine: O = Sum(Op)/lsum
    attn_combine_k<<<2048, 256, 0, stream>>>(Op0, Op1, Op2, Op3, lsum, Ob);

    // OUT: (8192 x 512) = O @ wpT^T + bp + x, 64-row tiles -> 512 blocks
    gemm128_k<3><<<dim3(128, 4, 1), 256, 0, stream>>>(
        Ob, wpT, bp, x, out, nullptr, nullptr, nullptr, nullptr);
}

// Round 11
// 308.894 us; speedup vs baseline: 1.0823x; 1.0823x over previous
//
#include <hip/hip_runtime.h>

// ---------------------------------------------------------------------------
// AttentionBlock: GroupNorm(32) -> q,k,v = xn@W+b -> softmax(q k^T / sqrt(C)) v
//                 -> out@wp+bp + x.   B=2, H=W=64, C=512, S=4096 per batch.
// Round 11: pure revert of r10's launch-bounds experiment.
//   EMPIRICAL LAW (r3/r4/r5/r10 data): for 256-thr blocks this toolchain
//   caps arch-VGPRs at ~256/arg for __launch_bounds__(256,arg):
//   arg=2 -> 128 cap (clean, 124-128 used), arg=4 -> 64 cap -> acc spills
//   (r10: +45 MB scratch WRITE on S, 82->102 us). Residency was already
//   ~3 blocks/CU at arg=2 (r8 Occupancy 37%), so arg=4 had no upside.
//   Keeps r9's verified wins: gn partial-sum (512 blocks), TM=64 OUT
//   (512 blocks), r8-style direct scattered P stores in the S epilogue.
// ---------------------------------------------------------------------------

typedef __bf16 bf16_t;
typedef __bf16 bf16x8 __attribute__((ext_vector_type(8)));
typedef __bf16 bf16x4 __attribute__((ext_vector_type(4)));
typedef float  f32x4  __attribute__((ext_vector_type(4)));

__device__ __forceinline__ bf16x8 ld8(const bf16_t* p) {
    return *reinterpret_cast<const bf16x8*>(p);
}
__device__ __forceinline__ f32x4 mfma16(bf16x8 a, bf16x8 b, f32x4 c) {
    return __builtin_amdgcn_mfma_f32_16x16x32_bf16(a, b, c, 0, 0, 0);
}
__device__ __forceinline__ void gload16(const bf16_t* gp, bf16_t* lp) {
    // HW semantics: LDS dest = wave-uniform base + laneid*16B; gp per-lane.
    __builtin_amdgcn_global_load_lds(
        (const __attribute__((address_space(1))) void*)gp,
        (__attribute__((address_space(3))) void*)lp, 16, 0, 0);
}

#define NPIX 8192      // B*H*W
#define C512 512
#define SEQ  4096      // H*W per batch
#define QSCALE 0.044194173824159216f   // 512^-0.5

// ---------------- GroupNorm partial sums: 512 blocks (8 slices x 64 bg) -----
__global__ __launch_bounds__(256) void gn_sum_k(const float* __restrict__ x,
                                                float* __restrict__ accum) {
    int bg    = blockIdx.x >> 3;        // 0..63 = b*32+g
    int slice = blockIdx.x & 7;         // 512-pixel slice
    int b = bg >> 5, g = bg & 31;
    const float* xp = x + (size_t)b * SEQ * C512 + g * 16;
    float s = 0.f, s2 = 0.f;
    #pragma unroll
    for (int pp = 0; pp < 2; pp++) {
        int p = slice * 512 + pp * 256 + threadIdx.x;
        const float4* q = reinterpret_cast<const float4*>(xp + (size_t)p * C512);
        #pragma unroll
        for (int i = 0; i < 4; i++) {
            float4 v = q[i];
            s  += v.x + v.y + v.z + v.w;
            s2 += v.x*v.x + v.y*v.y + v.z*v.z + v.w*v.w;
        }
    }
    #pragma unroll
    for (int off = 32; off >= 1; off >>= 1) {
        s  += __shfl_down(s, off);
        s2 += __shfl_down(s2, off);
    }
    __shared__ float rs[4], rs2[4];
    int wave = threadIdx.x >> 6;
    if ((threadIdx.x & 63) == 0) { rs[wave] = s; rs2[wave] = s2; }
    __syncthreads();
    if (threadIdx.x == 0) {
        float S = rs[0] + rs[1] + rs[2] + rs[3];
        float S2 = rs2[0] + rs2[1] + rs2[2] + rs2[3];
        atomicAdd(&accum[bg * 2],     S);
        atomicAdd(&accum[bg * 2 + 1], S2);
    }
}

// ---------------- weights: fp32 (k,n) -> bf16 transposed (n,k) --------------
__global__ __launch_bounds__(256) void wt_conv_k(const float* wq, const float* wk,
                                                 const float* wv, const float* wp,
                                                 bf16_t* wqkvT, bf16_t* wpT) {
    int y = blockIdx.y;
    const float* w = (y == 0) ? wq : (y == 1) ? wk : (y == 2) ? wv : wp;
    float scale = (y == 0) ? QSCALE : 1.0f;
    int tid = blockIdx.x * 256 + threadIdx.x;     // 262144 total
    int n = tid >> 9, k = tid & 511;
    bf16_t val = (bf16_t)(w[(size_t)k * C512 + n] * scale);
    if (y < 3) wqkvT[((size_t)y * C512 + n) * C512 + k] = val;
    else       wpT[(size_t)n * C512 + k] = val;
}

// ---------------- merged qkv bias (Q segment pre-scaled) --------------------
__global__ __launch_bounds__(256) void bias_merge_k(const float* bq, const float* bk,
                                                    const float* bv, float* bqkv) {
    int i = blockIdx.x * 256 + threadIdx.x;       // 1536
    float v = (i < 512) ? bq[i] * QSCALE : (i < 1024) ? bk[i - 512] : bv[i - 1024];
    bqkv[i] = v;
}

// ---------------- xn = groupnorm(x)*gamma+beta -> bf16 ----------------------
// accum holds raw (sum, sumsq) per (b,g); finalize inline.
__global__ __launch_bounds__(256) void xn_k(const float* __restrict__ x,
                                            const float* __restrict__ accum,
                                            const float* __restrict__ gamma,
                                            const float* __restrict__ beta,
                                            bf16_t* __restrict__ xn) {
    size_t idx = ((size_t)blockIdx.x * 256 + threadIdx.x) * 4;   // elem index
    int c = (int)(idx & 511);
    size_t pix = idx >> 9;
    int b = (int)(pix >> 12);
    int g = c >> 4;
    float sum = accum[(b * 32 + g) * 2];
    float ssq = accum[(b * 32 + g) * 2 + 1];
    float mean = sum * (1.f / 65536.f);
    float var  = ssq * (1.f / 65536.f) - mean * mean;
    float rstd = rsqrtf(var + 1e-5f);
    float4 v  = *reinterpret_cast<const float4*>(x + idx);
    float4 gm = *reinterpret_cast<const float4*>(gamma + c);
    float4 bt = *reinterpret_cast<const float4*>(beta + c);
    bf16x4 o;
    o[0] = (bf16_t)((v.x - mean) * rstd * gm.x + bt.x);
    o[1] = (bf16_t)((v.y - mean) * rstd * gm.y + bt.y);
    o[2] = (bf16_t)((v.z - mean) * rstd * gm.z + bt.z);
    o[3] = (bf16_t)((v.w - mean) * rstd * gm.w + bt.w);
    *reinterpret_cast<bf16x4*>(xn + idx) = o;
}

// ---------------- unified TMx128-tile GEMM (m97 structure) ------------------
// C[TM,128] per block = A[TM,K] x B^T where B is n-major [n][k].
// Block 256 thr / 4 waves (2x2 of (TM/2)x64). BK=32. global_load_lds staging
// into fragment-major LDS (conflict-free, proven). __launch_bounds__(256,2):
// VGPR cap 128 (see header law) — acc in AGPRs, no spill, ~3 blocks/CU.
// MODE 0: QKV (TM=128) — A=xn, B=wqkvT(1536x512). Epilogue: +bqkv; cols
//                0-511 -> Q, 512-1023 -> K (row-major), 1024-1535 -> VT.
// MODE 1: S   (TM=128) — per batch z: A=Q, B=K. Epilogue: P=exp(min(s,20))
//                direct bf16 stores; fp32 row-sums shfl-reduced, atomicAdd
//                into lsum.
// MODE 2: PV  (TM=128) — split-K x4: z=b*4+sp. A=P(lda=SEQ), B=VT(ldb=SEQ).
//                Unnormalized bf16 partial into Op[sp].
// MODE 3: OUT (TM=64)  — A=O, B=wpT. Epilogue: +bp +resid, fp32 out.
template <int MODE>
__global__ __launch_bounds__(256, 2) void gemm128_k(
        const bf16_t* __restrict__ Aall, const bf16_t* __restrict__ Ball,
        const float* __restrict__ bias, const float* __restrict__ resid,
        void* __restrict__ out0, void* __restrict__ out1,
        void* __restrict__ out2, void* __restrict__ out3,
        float* __restrict__ lsum) {
    constexpr int TM  = (MODE == 3) ? 64 : 128;
    constexpr int ASZ = TM * 32;          // A elems per buffer
    constexpr int ACH = TM / 16;          // A chunks per step
    constexpr int CPW = (ACH + 8) / 4;    // staging chunks per wave
    constexpr int MI  = TM / 32;          // m-tiles per wave
    __shared__ bf16_t smem[2 * ASZ + 8192];   // A dbuf + B dbuf

    int lane = threadIdx.x & 63;
    int w    = threadIdx.x >> 6;          // 4 waves, 2x2
    int wr   = w >> 1, wc = w & 1;
    int lrow = lane & 15, quad = lane >> 4;
    int bz   = blockIdx.z;

    const bf16_t* A;
    const bf16_t* B;
    size_t lda, ldb;
    int ksteps, kofs = 0, zb = bz, sp = 0;
    if (MODE == 0)      { A = Aall;                         B = Ball;                        lda = 512;  ldb = 512;  ksteps = 16; }
    else if (MODE == 1) { A = Aall + (size_t)bz*SEQ*C512;   B = Ball + (size_t)bz*SEQ*C512;  lda = 512;  ldb = 512;  ksteps = 16; }
    else if (MODE == 2) { zb = bz >> 2; sp = bz & 3;
                          A = Aall + (size_t)zb*SEQ*SEQ;    B = Ball + (size_t)zb*C512*SEQ;  lda = SEQ;  ldb = SEQ;  ksteps = 32; kofs = sp * 1024; }
    else                { A = Aall;                         B = Ball;                        lda = 512;  ldb = 512;  ksteps = 16; }

    int bm = blockIdx.x * TM, bn = blockIdx.y * 128;

    // stage K-step ks into buffer buf: ACH A-chunks + 8 B-chunks
    auto stage = [&](int buf, int ks) {
        size_t k0 = (size_t)kofs + (size_t)ks * 32;
        #pragma unroll
        for (int ii = 0; ii < CPW; ii++) {
            int c = w * CPW + ii;
            if (c < ACH) {
                const bf16_t* gpA = A + (size_t)(bm + c * 16 + lrow) * lda + k0 + quad * 8;
                gload16(gpA, &smem[buf * ASZ + c * 512]);
            } else {
                int cb = c - ACH;
                const bf16_t* gpB = B + (size_t)(bn + cb * 16 + lrow) * ldb + k0 + quad * 8;
                gload16(gpB, &smem[2 * ASZ + buf * 4096 + cb * 512]);
            }
        }
    };

    f32x4 acc[MI][4] = {};

    stage(0, 0);

    for (int ks = 0; ks < ksteps; ks++) {
        int cur = ks & 1;
        __syncthreads();                 // drains stage(ks); WAR for dbuf
        if (ks + 1 < ksteps) stage(1 - cur, ks + 1);

        const bf16_t* al = &smem[cur * ASZ + (wr * MI) * 512];
        const bf16_t* bl = &smem[2 * ASZ + cur * 4096 + (wc * 4) * 512];
        bf16x8 af[MI], bf[4];
        #pragma unroll
        for (int m = 0; m < MI; m++) af[m] = ld8(al + m * 512 + lane * 8);
        #pragma unroll
        for (int n = 0; n < 4; n++) bf[n] = ld8(bl + n * 512 + lane * 8);
        #pragma unroll
        for (int m = 0; m < MI; m++)
            #pragma unroll
            for (int n = 0; n < 4; n++)
                acc[m][n] = mfma16(af[m], bf[n], acc[m][n]);
    }

    // ---- epilogue; C/D layout: col=lane&15, row=quad*4+reg ----
    float rs[MI][4];                     // MODE 1 per-row partial sums
    if (MODE == 1) {
        #pragma unroll
        for (int m = 0; m < MI; m++)
            #pragma unroll
            for (int i = 0; i < 4; i++) rs[m][i] = 0.f;
    }

    #pragma unroll
    for (int m = 0; m < MI; m++) {
        int rowb = bm + wr * (TM / 2) + m * 16 + quad * 4;
        #pragma unroll
        for (int n = 0; n < 4; n++) {
            int col = bn + wc * 64 + n * 16 + lrow;
            #pragma unroll
            for (int i = 0; i < 4; i++) {
                int row = rowb + i;
                float v = acc[m][n][i];
                if (MODE == 0) {
                    int seg = col >> 9, c = col & 511;
                    bf16_t val = (bf16_t)(v + bias[col]);
                    if (seg == 0) {
                        ((bf16_t*)out0)[(size_t)row * C512 + c] = val;
                    } else if (seg == 1) {
                        ((bf16_t*)out1)[(size_t)row * C512 + c] = val;
                    } else {
                        int b = row >> 12, s = row & 4095;
                        ((bf16_t*)out2)[((size_t)(b * C512 + c)) * SEQ + s] = val;
                    }
                } else if (MODE == 1) {
                    float p = __expf(fminf(v, 20.0f));
                    bf16_t* P = (bf16_t*)out0 + (size_t)bz * SEQ * SEQ;
                    P[(size_t)row * SEQ + col] = (bf16_t)p;
                    rs[m][i] += p;
                } else if (MODE == 2) {
                    bf16_t* Ops = (bf16_t*)((sp == 0) ? out0 : (sp == 1) ? out1
                                          : (sp == 2) ? out2 : out3);
                    Ops[((size_t)zb * SEQ + row) * C512 + col] = (bf16_t)v;
                } else {
                    size_t idx = (size_t)row * C512 + col;
                    ((float*)out0)[idx] = v + bias[col] + resid[idx];
                }
            }
        }
    }

    if (MODE == 1) {
        // reduce row sums over the 16 col-lanes, one atomicAdd/row/wave
        #pragma unroll
        for (int m = 0; m < MI; m++) {
            #pragma unroll
            for (int i = 0; i < 4; i++) {
                float r = rs[m][i];
                r += __shfl_xor(r, 1);
                r += __shfl_xor(r, 2);
                r += __shfl_xor(r, 4);
                r += __shfl_xor(r, 8);
                if (lrow == 0) {
                    int row = bm + wr * 64 + m * 16 + quad * 4 + i;
                    atomicAdd(&lsum[(size_t)bz * SEQ + row], r);
                }
            }
        }
    }
}

// ---------------- combine PV split-K partials: O = Sum(Op)/lsum -------------
__global__ __launch_bounds__(256) void attn_combine_k(const bf16_t* __restrict__ Op0,
                                                      const bf16_t* __restrict__ Op1,
                                                      const bf16_t* __restrict__ Op2,
                                                      const bf16_t* __restrict__ Op3,
                                                      const float* __restrict__ lsum,
                                                      bf16_t* __restrict__ O) {
    int idx = blockIdx.x * 256 + threadIdx.x;    // 524288 threads
    int row = idx >> 6;                          // global row 0..8191
    int c8  = (idx & 63) << 3;
    float inv = 1.0f / lsum[row];
    size_t base = (size_t)row * C512 + c8;
    bf16x8 o0 = ld8(Op0 + base), o1 = ld8(Op1 + base);
    bf16x8 o2 = ld8(Op2 + base), o3 = ld8(Op3 + base);
    bf16x8 o;
    #pragma unroll
    for (int j = 0; j < 8; j++)
        o[j] = (bf16_t)(((float)o0[j] + (float)o1[j] +
                         (float)o2[j] + (float)o3[j]) * inv);
    *reinterpret_cast<bf16x8*>(O + base) = o;
}

// ---------------------------------------------------------------------------
extern "C" void kernel_launch(void* const* d_in, const int* in_sizes, int n_in,
                              void* d_out, int out_size, void* d_ws, size_t ws_size,
                              hipStream_t stream) {
    const float* x     = (const float*)d_in[0];
    const float* gamma = (const float*)d_in[1];
    const float* beta  = (const float*)d_in[2];
    const float* wq = (const float*)d_in[3];  const float* bq = (const float*)d_in[4];
    const float* wk = (const float*)d_in[5];  const float* bk = (const float*)d_in[6];
    const float* wv = (const float*)d_in[7];  const float* bv = (const float*)d_in[8];
    const float* wp = (const float*)d_in[9];  const float* bp = (const float*)d_in[10];
    float* out = (float*)d_out;

    char* ws = (char*)d_ws;
    size_t off = 0;
    float*  bqkv   = (float*)(ws + off);   off += 1536 * sizeof(float);
    float*  lsum   = (float*)(ws + off);   off += (size_t)NPIX * sizeof(float);
    float*  accum  = (float*)(ws + off);   off += 128 * sizeof(float);
    bf16_t* xn     = (bf16_t*)(ws + off);  off += (size_t)NPIX * C512 * 2;  // later Ob
    bf16_t* wqkvT  = (bf16_t*)(ws + off);  off += (size_t)3 * C512 * C512 * 2;
    bf16_t* wpT    = (bf16_t*)(ws + off);  off += (size_t)C512 * C512 * 2;
    bf16_t* Qb     = (bf16_t*)(ws + off);  off += (size_t)NPIX * C512 * 2;  // later Op0
    bf16_t* Kb     = (bf16_t*)(ws + off);  off += (size_t)NPIX * C512 * 2;  // later Op1
    bf16_t* VTb    = (bf16_t*)(ws + off);  off += (size_t)NPIX * C512 * 2;
    bf16_t* Op2    = (bf16_t*)(ws + off);  off += (size_t)NPIX * C512 * 2;
    bf16_t* Op3    = (bf16_t*)(ws + off);  off += (size_t)NPIX * C512 * 2;
    bf16_t* P      = (bf16_t*)(ws + off);  off += (size_t)2 * SEQ * SEQ * 2;  // 64 MB
    bf16_t* Ob  = xn;    // xn dead after QKV GEMM
    bf16_t* Op0 = Qb;    // Q dead after S GEMM
    bf16_t* Op1 = Kb;    // K dead after S GEMM

    // zero lsum + accum (contiguous)
    hipMemsetAsync(lsum, 0, (size_t)(NPIX + 128) * sizeof(float), stream);

    gn_sum_k<<<512, 256, 0, stream>>>(x, accum);
    wt_conv_k<<<dim3(1024, 4), 256, 0, stream>>>(wq, wk, wv, wp, wqkvT, wpT);
    bias_merge_k<<<6, 256, 0, stream>>>(bq, bk, bv, bqkv);
    xn_k<<<4096, 256, 0, stream>>>(x, accum, gamma, beta, xn);

    // QKV: (8192 x 1536) = xn @ wqkvT^T
    gemm128_k<0><<<dim3(64, 12, 1), 256, 0, stream>>>(
        xn, wqkvT, bqkv, nullptr, Qb, Kb, VTb, nullptr, nullptr);

    // S/P: per batch (4096 x 4096) = Q @ K^T, epilogue exp -> P, rowsums->lsum
    gemm128_k<1><<<dim3(32, 32, 2), 256, 0, stream>>>(
        Qb, Kb, nullptr, nullptr, P, nullptr, nullptr, nullptr, lsum);

    // PV: split-K x4 per batch (4096 x 512) = P @ VT^T -> 4 bf16 partials
    gemm128_k<2><<<dim3(32, 4, 8), 256, 0, stream>>>(
        P, VTb, nullptr, nullptr, Op0, Op1, Op2, Op3, nullptr);

    // combine: O = Sum(Op)/lsum
    attn_combine_k<<<2048, 256, 0, stream>>>(Op0, Op1, Op2, Op3, lsum, Ob);

    // OUT: (8192 x 512) = O @ wpT^T + bp + x, 64-row tiles -> 512 blocks
    gemm128_k<3><<<dim3(128, 4, 1), 256, 0, stream>>>(
        Ob, wpT, bp, x, out, nullptr, nullptr, nullptr, nullptr);
}